// Round 14
// baseline (4901.867 us; speedup 1.0000x reference)
//
#include <hip/hip_runtime.h>
#include <hip/hip_bf16.h>

#define T_STEPS 512
#define BATCH   64
#define HID     1024
#define NWG     128         // 4 row-groups x 32 col-slices (32 cols each)
#define NSLOT   32          // rotating exchange slots
#define SLOT_SH (4 * 16 * 1024)   // shorts per slot

typedef __attribute__((ext_vector_type(8))) short short8;
typedef __attribute__((ext_vector_type(4))) float f32x4;
typedef __attribute__((ext_vector_type(4))) int  i32x4;

static __device__ __forceinline__ float b2f(unsigned short u){
  union { unsigned u; float f; } c; c.u = ((unsigned)u) << 16; return c.f;
}
static __device__ __forceinline__ unsigned short f2b(float f){
  union { float f; unsigned u; } c; c.f = f;
  unsigned r = c.u + 0x7fffu + ((c.u >> 16) & 1u);
  return (unsigned short)(r >> 16);
}
static __device__ __forceinline__ float sigm(float x){ return 1.0f / (1.0f + __expf(-x)); }
static __device__ __forceinline__ float tanh_fast(float x){ return 2.0f / (1.0f + __expf(-2.0f * x)) - 1.0f; }

#define MFMA __builtin_amdgcn_mfma_f32_16x16x32_bf16

// ---------------- init: zero barrier flags (1 flag per 128B line) ----------------
__global__ void gru_init_k(int* __restrict__ flags){
  int i = blockIdx.x * blockDim.x + threadIdx.x;
  if (i < 4 * 32 * 32)
    __hip_atomic_store(flags + i, 0, __ATOMIC_RELAXED, __HIP_MEMORY_SCOPE_AGENT);
}

// ---------------- transpose + cast weights: Wt[g][n][k] = W_g[k][n] ----------------
__global__ void gru_prepw_k(const float* __restrict__ w0, const float* __restrict__ w1,
                            const float* __restrict__ w2, const float* __restrict__ w3,
                            const float* __restrict__ w4, const float* __restrict__ w5,
                            unsigned short* __restrict__ wt){
  __shared__ float tile[32][33];
  const float* src;
  switch (blockIdx.z){
    case 0: src = w0; break; case 1: src = w1; break; case 2: src = w2; break;
    case 3: src = w3; break; case 4: src = w4; break; default: src = w5; break;
  }
  int tx = threadIdx.x, ty = threadIdx.y;
  int x0 = blockIdx.x * 32, y0 = blockIdx.y * 32;
  #pragma unroll
  for (int i = 0; i < 32; i += 8)
    tile[ty + i][tx] = src[(size_t)(y0 + ty + i) * HID + x0 + tx];
  __syncthreads();
  unsigned short* dst = wt + (size_t)blockIdx.z * HID * HID;
  #pragma unroll
  for (int i = 0; i < 32; i += 8)
    dst[(size_t)(x0 + ty + i) * HID + y0 + tx] = f2b(tile[tx][ty + i]);
}

// ---------------- pre-pass: G2[t][gate][col][row] = (X @ Wx + b), bf16 ----------
__global__ __launch_bounds__(256, 2) void gru_xproj_k(
    const float* __restrict__ inp,         // [32768][1024] fp32
    const unsigned short* __restrict__ wt, // x-weights slots 0,2,4
    const float* __restrict__ bz, const float* __restrict__ br, const float* __restrict__ bh,
    unsigned short* __restrict__ G2)       // [512][3][1024][64] bf16
{
  const int wv = threadIdx.x >> 6, lane = threadIdx.x & 63;
  const int l16 = lane & 15, kq = lane >> 4;
  const int m0 = blockIdx.x * 64;
  const int n0 = blockIdx.y * 256 + wv * 64;

  const unsigned short* wb[4];
  float bias[4];
  #pragma unroll
  for (int c = 0; c < 4; ++c){
    int n = n0 + c * 16 + l16;
    int g = n >> 10, cc = n & 1023;
    wb[c] = wt + (size_t)(2 * g) * HID * HID + (size_t)cc * HID + kq * 8;
    bias[c] = (g == 0 ? bz : (g == 1 ? br : bh))[cc];
  }
  const float* arow[4];
  #pragma unroll
  for (int r = 0; r < 4; ++r)
    arow[r] = inp + (size_t)(m0 + r * 16 + l16) * HID + kq * 8;

  f32x4 acc[4][4];
  #pragma unroll
  for (int r = 0; r < 4; ++r)
    #pragma unroll
    for (int c = 0; c < 4; ++c) acc[r][c] = (f32x4){0.f,0.f,0.f,0.f};

  #pragma unroll 2
  for (int kk = 0; kk < HID; kk += 32){
    short8 af[4], bf[4];
    #pragma unroll
    for (int r = 0; r < 4; ++r){
      float4 f0 = *(const float4*)(arow[r] + kk);
      float4 f1 = *(const float4*)(arow[r] + kk + 4);
      short8 a;
      a[0]=(short)f2b(f0.x); a[1]=(short)f2b(f0.y); a[2]=(short)f2b(f0.z); a[3]=(short)f2b(f0.w);
      a[4]=(short)f2b(f1.x); a[5]=(short)f2b(f1.y); a[6]=(short)f2b(f1.z); a[7]=(short)f2b(f1.w);
      af[r] = a;
    }
    #pragma unroll
    for (int c = 0; c < 4; ++c) bf[c] = *(const short8*)(wb[c] + kk);
    #pragma unroll
    for (int r = 0; r < 4; ++r)
      #pragma unroll
      for (int c = 0; c < 4; ++c)
        acc[r][c] = MFMA(af[r], bf[c], acc[r][c], 0, 0, 0);
  }

  #pragma unroll
  for (int c = 0; c < 4; ++c){
    int n = n0 + c * 16 + l16;
    int g = n >> 10, cc = n & 1023;
    #pragma unroll
    for (int r = 0; r < 4; ++r){
      unsigned lo = (unsigned)f2b(acc[r][c][0] + bias[c]) | ((unsigned)f2b(acc[r][c][1] + bias[c]) << 16);
      unsigned hi = (unsigned)f2b(acc[r][c][2] + bias[c]) | ((unsigned)f2b(acc[r][c][3] + bias[c]) << 16);
      *(unsigned long long*)&G2[((size_t)(blockIdx.x * 3 + g) * 1024 + cc) * 64 + r * 16 + kq * 4] =
        (unsigned long long)lo | ((unsigned long long)hi << 32);
    }
  }
}

// ---- poll: 32 lanes, one flag each (flags 128B apart), light backoff ----
static __device__ __forceinline__ void waitflags32(const int* fgrp, int target){
  const int lane = threadIdx.x & 63;
  const int* p = fgrp + (lane & 31) * 32;
  const bool mine = lane < 32;
  for (;;){
    int v = mine ? __hip_atomic_load(p, __ATOMIC_RELAXED, __HIP_MEMORY_SCOPE_AGENT)
                 : 0x7fffffff;
    if (__all(v >= target)) return;
    __builtin_amdgcn_s_sleep(1);
  }
}

// ---- stage 16x1024 bf16 tile (32KB): lane-contiguous 16B chunks, conflict-free writes ----
// tile byte b -> LDS byte b ^ ((b>>11 & 7)<<4)  (same mapping as the MFMA read side)
static __device__ __forceinline__ void stage_in(const unsigned short* __restrict__ src,
                                                unsigned short* __restrict__ stg, int tid){
  char* sb = (char*)stg;
  const char* sc = (const char*)src;
  #pragma unroll
  for (int c = 0; c < 4; ++c){
    const int b = tid * 16 + c * 8192;
    short8 v = __builtin_nontemporal_load((const short8*)(sc + b));
    *(short8*)(sb + (b ^ (((b >> 11) & 7) << 4))) = v;
  }
}

// ---- publish 16B write-through to MALL (sc0 sc1) ----
static __device__ __forceinline__ void pub16(unsigned short* dst, const unsigned short* lds_src){
  i32x4 v = *(const i32x4*)lds_src;
  asm volatile("global_store_dwordx4 %0, %1, off sc0 sc1" :: "v"(dst), "v"(v) : "memory");
}

// ---------------- persistent GRU scan: 4 rg x 32 cs, weights in VGPRs ----------------
__global__ __launch_bounds__(512, 1) void gru_scan_k(
    const unsigned short* __restrict__ G2,    // [512][3][1024][64] bf16
    const unsigned short* __restrict__ wt,    // [6][1024][1024] bf16 [n][k]
    float* __restrict__ out,                  // [T][64][1024] fp32 + [64][1024] H_final
    unsigned short* __restrict__ hb,          // [NSLOT][4][16][1024] bf16 H slots
    unsigned short* __restrict__ rh,          // [NSLOT][4][16][1024] bf16 R*H slots
    int* __restrict__ flags)                  // [4][32][32] (128B-strided flags)
{
  __shared__ __align__(16) unsigned short stage[16 * 1024];  // 32 KiB staged H or R*H
  __shared__ float pbuf[2176];                               // 8.5 KiB split-K partials (stride 17)
  __shared__ float zlds[512];                                // own-slice Z [16][32]
  __shared__ float hlds[512];                                // own-slice H fp32
  __shared__ __align__(16) unsigned short ostage[512];       // 1 KiB publish tile

  const int bid = blockIdx.x;
  const int rg  = bid & 3;            // batch rows [rg*16, +16)
  const int cs  = bid >> 2;           // hid cols  [cs*32, +32)
  const int tid  = threadIdx.x;
  const int w    = tid >> 6;
  const int lane = tid & 63;
  const int l16  = lane & 15;
  const int kq   = lane >> 4;

  // phase-A role: gate (Z/R) x col-tile x K-half.  phase-B role: col-tile x K-quarter.
  const int gA = w & 1, ctA = (w >> 1) & 1, khA = w >> 2;
  const int ctB = w & 1, kqB = w >> 1;

  // reduce mapping: one thread per own-slice element
  const int rrow = tid >> 5, rcol = tid & 31;
  const int gcr  = cs * 32 + rcol;          // global hidden col
  const int grow = rg * 16 + rrow;          // global batch row
  const int eidx17 = rrow * 17 + (rcol & 15);
  const int ctR  = rcol >> 4;

  // ---- preload this WG's weight slice into registers (once; never re-read) ----
  short8 wA[16];
  {
    const unsigned short* p = wt + (size_t)(gA ? 3 : 1) * HID * HID
                            + (size_t)(cs * 32 + ctA * 16 + l16) * HID + khA * 512 + kq * 8;
    #pragma unroll
    for (int i = 0; i < 16; ++i) wA[i] = *(const short8*)(p + i * 32);
  }
  short8 wB[8];
  {
    const unsigned short* p = wt + (size_t)5 * HID * HID
                            + (size_t)(cs * 32 + ctB * 16 + l16) * HID + kqB * 256 + kq * 8;
    #pragma unroll
    for (int i = 0; i < 8; ++i) wB[i] = *(const short8*)(p + i * 32);
  }

  int* fgrp   = flags + rg * 32 * 32;
  int* myflag = fgrp + cs * 32;

  hlds[tid] = 0.f;
  __syncthreads();

  const int asw = (l16 & 7) << 4;
  const int aA  = l16 * 2048 + khA * 1024 + kq * 16;   // + i*64, then ^asw
  const int aB  = l16 * 2048 + kqB * 512  + kq * 16;

  const int prow64 = tid >> 2, pc8 = (tid & 3) * 8;    // publish mapping (tid<64)

  for (int t = 0; t < T_STEPS; ++t){
    unsigned short* hb_w = hb + (size_t)(t & (NSLOT - 1)) * SLOT_SH + rg * 16384;
    unsigned short* rh_w = rh + (size_t)(t & (NSLOT - 1)) * SLOT_SH + rg * 16384;
    const unsigned short* hb_r = hb + (size_t)((t - 1) & (NSLOT - 1)) * SLOT_SH + rg * 16384;

    // prefetch x-gate scalars (cached; before any wait)
    const size_t gstep = (size_t)t * 3 * 1024 * 64;
    const float gxz = b2f(G2[gstep + ((size_t)0 * 1024 + gcr) * 64 + grow]);
    const float gxr = b2f(G2[gstep + ((size_t)1 * 1024 + gcr) * 64 + grow]);
    const float gxh = b2f(G2[gstep + ((size_t)2 * 1024 + gcr) * 64 + grow]);

    // ---- phase A: H_{t-1} @ {Whz,Whr} (split gate/ct/khalf across 8 waves) ----
    if (t){
      if (w == 0) waitflags32(fgrp, 2 * t);
      __syncthreads();
      stage_in(hb_r, stage, tid);
      __syncthreads();
      const char* sb = (const char*)stage;
      f32x4 acc = {0.f, 0.f, 0.f, 0.f};
      #pragma unroll
      for (int i = 0; i < 16; ++i){
        short8 af = *(const short8*)(sb + ((aA + i * 64) ^ asw));
        acc = MFMA(af, wA[i], acc, 0, 0, 0);
      }
      #pragma unroll
      for (int j = 0; j < 4; ++j)
        pbuf[((gA * 2 + khA) * 2 + ctA) * 272 + (kq * 4 + j) * 17 + l16] = acc[j];
    }
    __syncthreads();                                   // pbuf ready (or t==0)
    {
      float pz = t ? (pbuf[(0 + ctR) * 272 + eidx17] + pbuf[(2 + ctR) * 272 + eidx17]) : 0.f;
      float pr = t ? (pbuf[(4 + ctR) * 272 + eidx17] + pbuf[(6 + ctR) * 272 + eidx17]) : 0.f;
      float z  = sigm(pz + gxz);
      float r  = sigm(pr + gxr);
      zlds[tid]   = z;
      ostage[tid] = f2b(r * hlds[tid]);
    }
    __syncthreads();                                   // ostage ready; pbuf reusable
    if (t){
      // wave-0-only publish; wave-0 scalar vmcnt(0) covers all 64 lanes' stores
      if (tid < 64) pub16(rh_w + prow64 * 1024 + cs * 32 + pc8, &ostage[prow64 * 32 + pc8]);
      if (tid == 0){
        asm volatile("s_waitcnt vmcnt(0)" ::: "memory");
        __hip_atomic_store(myflag, 2 * t + 1, __ATOMIC_RELAXED, __HIP_MEMORY_SCOPE_AGENT);
      }
      // ---- phase B: (R*H) @ Whh (split ct/kquarter across 8 waves) ----
      if (w == 0) waitflags32(fgrp, 2 * t + 1);
      __syncthreads();
      stage_in(rh_w, stage, tid);
      __syncthreads();
      const char* sb = (const char*)stage;
      f32x4 acc = {0.f, 0.f, 0.f, 0.f};
      #pragma unroll
      for (int i = 0; i < 8; ++i){
        short8 af = *(const short8*)(sb + ((aB + i * 64) ^ asw));
        acc = MFMA(af, wB[i], acc, 0, 0, 0);
      }
      #pragma unroll
      for (int j = 0; j < 4; ++j)
        pbuf[(kqB * 2 + ctB) * 272 + (kq * 4 + j) * 17 + l16] = acc[j];
    }
    __syncthreads();                                   // pbuf ready (or t==0)
    float hn;
    {
      float ph = t ? (pbuf[(0 + ctR) * 272 + eidx17] + pbuf[(2 + ctR) * 272 + eidx17]
                    + pbuf[(4 + ctR) * 272 + eidx17] + pbuf[(6 + ctR) * 272 + eidx17]) : 0.f;
      float ht = tanh_fast(ph + gxh);
      float z  = zlds[tid], hp = hlds[tid];
      hn = z * hp + (1.0f - z) * ht;
      hlds[tid]   = hn;
      ostage[tid] = f2b(hn);
    }
    __syncthreads();                                   // ostage/hlds complete
    if (t < T_STEPS - 1){
      if (tid < 64) pub16(hb_w + prow64 * 1024 + cs * 32 + pc8, &ostage[prow64 * 32 + pc8]);
      if (tid == 0){
        asm volatile("s_waitcnt vmcnt(0)" ::: "memory");
        __hip_atomic_store(myflag, 2 * t + 2, __ATOMIC_RELAXED, __HIP_MEMORY_SCOPE_AGENT);
      }
    }
    // out stores: after the flag release, fully off the critical path
    __builtin_nontemporal_store(hn, &out[((size_t)t * BATCH + grow) * HID + gcr]);
    if (t == T_STEPS - 1)
      __builtin_nontemporal_store(hn, &out[(size_t)T_STEPS * BATCH * HID + (size_t)grow * HID + gcr]);
  }
}

extern "C" void kernel_launch(void* const* d_in, const int* in_sizes, int n_in,
                              void* d_out, int out_size, void* d_ws, size_t ws_size,
                              hipStream_t stream){
  const float* inputs = (const float*)d_in[0];
  const float* W_xz = (const float*)d_in[1];
  const float* W_hz = (const float*)d_in[2];
  const float* b_z  = (const float*)d_in[3];
  const float* W_xr = (const float*)d_in[4];
  const float* W_hr = (const float*)d_in[5];
  const float* b_r  = (const float*)d_in[6];
  const float* W_xh = (const float*)d_in[7];
  const float* W_hh = (const float*)d_in[8];
  const float* b_h  = (const float*)d_in[9];
  float* out = (float*)d_out;

  char* ws = (char*)d_ws;
  int*            flags = (int*)ws;                                  // 16 KiB (128B-strided)
  unsigned short* hb    = (unsigned short*)(ws + 16384);             // 4 MiB (32 slots)
  unsigned short* rh    = (unsigned short*)(ws + 16384 + 4194304);   // 4 MiB
  unsigned short* wt    = (unsigned short*)(ws + 16384 + 8388608);   // 12 MiB
  unsigned short* G2    = (unsigned short*)(ws + 16384 + 8388608 + 12582912); // 192 MiB
  // total ws needed: ~212 MB

  gru_init_k<<<16, 256, 0, stream>>>(flags);
  gru_prepw_k<<<dim3(32, 32, 6), dim3(32, 8), 0, stream>>>(W_xz, W_hz, W_xr, W_hr, W_xh, W_hh, wt);
  gru_xproj_k<<<dim3(512, 12), 256, 0, stream>>>(inputs, wt, b_z, b_r, b_h, G2);
  gru_scan_k<<<NWG, 512, 0, stream>>>(G2, wt, out, hb, rh, flags);
}

// Round 15
// 3789.554 us; speedup vs baseline: 1.2935x; 1.2935x over previous
//
#include <hip/hip_runtime.h>
#include <hip/hip_bf16.h>

#define T_STEPS 512
#define BATCH   64
#define HID     1024
#define NWG     128         // 4 row-groups x 32 col-slices (32 cols each)
#define NSLOT   32          // rotating exchange slots
#define SLOT_SH (4 * 16 * 1024)   // shorts per slot

typedef __attribute__((ext_vector_type(8))) short short8;
typedef __attribute__((ext_vector_type(4))) float f32x4;
typedef __attribute__((ext_vector_type(4))) int  i32x4;

static __device__ __forceinline__ float b2f(unsigned short u){
  union { unsigned u; float f; } c; c.u = ((unsigned)u) << 16; return c.f;
}
static __device__ __forceinline__ unsigned short f2b(float f){
  union { float f; unsigned u; } c; c.f = f;
  unsigned r = c.u + 0x7fffu + ((c.u >> 16) & 1u);
  return (unsigned short)(r >> 16);
}
static __device__ __forceinline__ float sigm(float x){ return 1.0f / (1.0f + __expf(-x)); }
static __device__ __forceinline__ float tanh_fast(float x){ return 2.0f / (1.0f + __expf(-2.0f * x)) - 1.0f; }

#define MFMA __builtin_amdgcn_mfma_f32_16x16x32_bf16

// ---------------- init: zero barrier flags (1 flag per 128B line) ----------------
__global__ void gru_init_k(int* __restrict__ flags){
  int i = blockIdx.x * blockDim.x + threadIdx.x;
  if (i < 4 * 32 * 32)
    __hip_atomic_store(flags + i, 0, __ATOMIC_RELAXED, __HIP_MEMORY_SCOPE_AGENT);
}

// ---------------- transpose + cast weights: Wt[g][n][k] = W_g[k][n] ----------------
__global__ void gru_prepw_k(const float* __restrict__ w0, const float* __restrict__ w1,
                            const float* __restrict__ w2, const float* __restrict__ w3,
                            const float* __restrict__ w4, const float* __restrict__ w5,
                            unsigned short* __restrict__ wt){
  __shared__ float tile[32][33];
  const float* src;
  switch (blockIdx.z){
    case 0: src = w0; break; case 1: src = w1; break; case 2: src = w2; break;
    case 3: src = w3; break; case 4: src = w4; break; default: src = w5; break;
  }
  int tx = threadIdx.x, ty = threadIdx.y;
  int x0 = blockIdx.x * 32, y0 = blockIdx.y * 32;
  #pragma unroll
  for (int i = 0; i < 32; i += 8)
    tile[ty + i][tx] = src[(size_t)(y0 + ty + i) * HID + x0 + tx];
  __syncthreads();
  unsigned short* dst = wt + (size_t)blockIdx.z * HID * HID;
  #pragma unroll
  for (int i = 0; i < 32; i += 8)
    dst[(size_t)(x0 + ty + i) * HID + y0 + tx] = f2b(tile[tx][ty + i]);
}

// ---------------- pre-pass: G2[t][gate][col][row] = (X @ Wx + b), bf16 ----------
// block: 32 batch-rows x ONE gate (1024 cols). A-tile staged once in LDS (bf16).
// grid (1024, 3): x -> 32-row tile (t = x>>1, rbase = (x&1)*32), y -> gate.
__global__ __launch_bounds__(512, 1) void gru_xproj_k(
    const float* __restrict__ inp,         // [32768][1024] fp32
    const unsigned short* __restrict__ wt, // x-weights slots 0,2,4
    const float* __restrict__ bz, const float* __restrict__ br, const float* __restrict__ bh,
    unsigned short* __restrict__ G2)       // [512][3][1024][64] bf16
{
  __shared__ __align__(16) unsigned short albs[32 * 1024];   // 64 KiB swizzled A-tile

  const int tid = threadIdx.x, wv = tid >> 6, lane = tid & 63;
  const int l16 = lane & 15, kq = lane >> 4;
  const int tt = blockIdx.x >> 1;
  const int rbase = (blockIdx.x & 1) * 32;
  const int g = blockIdx.y;
  const float* bias_p = (g == 0) ? bz : (g == 1) ? br : bh;

  // stage + convert A: 32 rows x 1024 k, fp32 -> bf16, swizzle byte b ^ ((b>>11&7)<<4)
  char* sb = (char*)albs;
  const float* abase = inp + ((size_t)tt * 64 + rbase) * HID;
  #pragma unroll
  for (int p = 0; p < 16; ++p){
    int e = (p * 512 + tid) * 4;                 // element in [32][1024]
    float4 v = *(const float4*)(abase + e);
    ushort4 o;
    o.x = f2b(v.x); o.y = f2b(v.y); o.z = f2b(v.z); o.w = f2b(v.w);
    int b = e * 2;
    *(ushort4*)(sb + (b ^ (((b >> 11) & 7) << 4))) = o;
  }
  __syncthreads();

  const int n0 = wv * 128;
  const unsigned short* wslab = wt + (size_t)(2 * g) * HID * HID;
  const unsigned short* wcol[8];
  float bias[8];
  #pragma unroll
  for (int c = 0; c < 8; ++c){
    int n = n0 + c * 16 + l16;
    wcol[c] = wslab + (size_t)n * HID + kq * 8;
    bias[c] = bias_p[n];
  }

  f32x4 acc[2][8];
  #pragma unroll
  for (int r = 0; r < 2; ++r)
    #pragma unroll
    for (int c = 0; c < 8; ++c) acc[r][c] = (f32x4){0.f,0.f,0.f,0.f};

  const int asw = (l16 & 7) << 4;
  for (int kk = 0; kk < HID; kk += 32){
    short8 a0 = *(const short8*)(sb + ((l16 * 2048 + kk * 2 + kq * 16) ^ asw));
    short8 a1 = *(const short8*)(sb + (((16 + l16) * 2048 + kk * 2 + kq * 16) ^ asw));
    #pragma unroll
    for (int c = 0; c < 8; ++c){
      short8 bf = *(const short8*)(wcol[c] + kk);
      acc[0][c] = MFMA(a0, bf, acc[0][c], 0, 0, 0);
      acc[1][c] = MFMA(a1, bf, acc[1][c], 0, 0, 0);
    }
  }

  unsigned short* gout = G2 + ((size_t)tt * 3 + g) * 65536;   // [1024][64]
  #pragma unroll
  for (int c = 0; c < 8; ++c){
    int n = n0 + c * 16 + l16;
    #pragma unroll
    for (int r = 0; r < 2; ++r){
      int row = rbase + r * 16 + kq * 4;
      unsigned lo = (unsigned)f2b(acc[r][c][0] + bias[c]) | ((unsigned)f2b(acc[r][c][1] + bias[c]) << 16);
      unsigned hi = (unsigned)f2b(acc[r][c][2] + bias[c]) | ((unsigned)f2b(acc[r][c][3] + bias[c]) << 16);
      *(unsigned long long*)&gout[(size_t)n * 64 + row] =
        (unsigned long long)lo | ((unsigned long long)hi << 32);
    }
  }
}

// ---- poll: 32 lanes, one flag each (flags 128B apart), light backoff ----
static __device__ __forceinline__ void waitflags32(const int* fgrp, int target){
  const int lane = threadIdx.x & 63;
  const int* p = fgrp + (lane & 31) * 32;
  const bool mine = lane < 32;
  for (;;){
    int v = mine ? __hip_atomic_load(p, __ATOMIC_RELAXED, __HIP_MEMORY_SCOPE_AGENT)
                 : 0x7fffffff;
    if (__all(v >= target)) return;
    __builtin_amdgcn_s_sleep(1);
  }
}

// ---- stage 16x1024 bf16 tile (32KB): lane-contiguous 16B chunks, conflict-free writes ----
static __device__ __forceinline__ void stage_in(const unsigned short* __restrict__ src,
                                                unsigned short* __restrict__ stg, int tid){
  char* sb = (char*)stg;
  const char* sc = (const char*)src;
  #pragma unroll
  for (int c = 0; c < 4; ++c){
    const int b = tid * 16 + c * 8192;
    short8 v = __builtin_nontemporal_load((const short8*)(sc + b));
    *(short8*)(sb + (b ^ (((b >> 11) & 7) << 4))) = v;
  }
}

// ---- publish 16B write-through to MALL (sc0 sc1) ----
static __device__ __forceinline__ void pub16(unsigned short* dst, const unsigned short* lds_src){
  i32x4 v = *(const i32x4*)lds_src;
  asm volatile("global_store_dwordx4 %0, %1, off sc0 sc1" :: "v"(dst), "v"(v) : "memory");
}

// ---------------- persistent GRU scan: full-K wave roles, no pbuf ----------------
// waves 0-1: Z (col-tiles 0,1) | waves 2-3: R | waves 4-5: H_tilde | waves 6-7: stage help
__global__ __launch_bounds__(512, 1) void gru_scan_k(
    const unsigned short* __restrict__ G2,    // [512][3][1024][64] bf16
    const unsigned short* __restrict__ wt,    // [6][1024][1024] bf16 [n][k]
    float* __restrict__ out,                  // [T][64][1024] fp32 + [64][1024] H_final
    unsigned short* __restrict__ hb,          // [NSLOT][4][16][1024] bf16 H slots
    unsigned short* __restrict__ rh,          // [NSLOT][4][16][1024] bf16 R*H slots
    int* __restrict__ flags)                  // [4][32][32] (128B-strided flags)
{
  __shared__ __align__(16) unsigned short stage[16 * 1024];  // 32 KiB staged H or R*H
  __shared__ float zlds[16 * 33];                            // own-slice Z (padded)
  __shared__ float hlds[16 * 33];                            // own-slice H fp32 (padded)
  __shared__ __align__(16) unsigned short ostage[512];       // 1 KiB publish tile

  const int bid = blockIdx.x;
  const int rg  = bid & 3;            // batch rows [rg*16, +16)
  const int cs  = bid >> 2;           // hid cols  [cs*32, +32)
  const int tid  = threadIdx.x;
  const int w    = tid >> 6;
  const int lane = tid & 63;
  const int l16  = lane & 15;
  const int kq   = lane >> 4;

  const int myct = (w < 4) ? (w & 1) : ((w < 6) ? (w - 4) : 0);
  const int col  = cs * 32 + myct * 16 + l16;   // this role's global hid col
  const int gA   = (w >> 1) & 1;                // waves0-1: Z(0), waves2-3: R(1)
  const int erow0 = kq * 4;                     // acc[j] -> batch row erow0+j
  const int ecol  = myct * 16 + l16;

  // ---- weights into registers, one array per wave role ----
  short8 wreg[32];
  if (w < 6){
    const int slot = (w < 2) ? 1 : (w < 4) ? 3 : 5;   // Whz / Whr / Whh
    const unsigned short* p = wt + (size_t)slot * HID * HID + (size_t)col * HID + kq * 8;
    #pragma unroll
    for (int i = 0; i < 32; ++i) wreg[i] = *(const short8*)(p + i * 32);
  }

  int* fgrp   = flags + rg * 32 * 32;
  int* myflag = fgrp + cs * 32;

  for (int i = tid; i < 16 * 33; i += 512) hlds[i] = 0.f;
  __syncthreads();

  const int asw = (l16 & 7) << 4;
  const int abase = l16 * 2048 + kq * 16;        // + i*64, then ^asw
  const int prow64 = tid >> 2, pc8 = (tid & 3) * 8;   // publish mapping (tid<64)

  for (int t = 0; t < T_STEPS; ++t){
    unsigned short* hb_w = hb + (size_t)(t & (NSLOT - 1)) * SLOT_SH + rg * 16384;
    unsigned short* rh_w = rh + (size_t)(t & (NSLOT - 1)) * SLOT_SH + rg * 16384;
    const unsigned short* hb_r = hb + (size_t)((t - 1) & (NSLOT - 1)) * SLOT_SH + rg * 16384;

    // per-role x-gate scalars (cached, before any wait): 4 rows x 1 col = one u64
    unsigned long long gx = 0;
    if (w < 6){
      const int gate = (w < 4) ? gA : 2;
      gx = *(const unsigned long long*)
           (G2 + (size_t)t * 196608 + ((size_t)gate * 1024 + col) * 64 + rg * 16 + erow0);
    }

    // ---- phase A: Z / R gates (waves 0-3, full K) ----
    if (t){
      if (w == 0) waitflags32(fgrp, 2 * t);
      __syncthreads();
      stage_in(hb_r, stage, tid);
      __syncthreads();
    }
    if (w < 4){
      f32x4 a0 = {0.f,0.f,0.f,0.f}, a1 = {0.f,0.f,0.f,0.f};
      if (t){
        const char* sb = (const char*)stage;
        #pragma unroll
        for (int i = 0; i < 32; i += 2){
          short8 f0 = *(const short8*)(sb + ((abase + i * 64) ^ asw));
          short8 f1 = *(const short8*)(sb + ((abase + i * 64 + 64) ^ asw));
          a0 = MFMA(f0, wreg[i],     a0, 0, 0, 0);
          a1 = MFMA(f1, wreg[i + 1], a1, 0, 0, 0);
        }
      }
      #pragma unroll
      for (int j = 0; j < 4; ++j){
        float g = sigm(a0[j] + a1[j] + b2f((unsigned short)(gx >> (16 * j))));
        if (w < 2) zlds[(erow0 + j) * 33 + ecol] = g;                       // Z
        else       ostage[(erow0 + j) * 32 + ecol] =
                     f2b(g * hlds[(erow0 + j) * 33 + ecol]);                // R*H
      }
    }
    __syncthreads();                                   // zlds / ostage complete

    // ---- exchange R*H, then phase B: H_tilde + combine (waves 4-5, full K) ----
    if (t){
      if (tid < 64) pub16(rh_w + prow64 * 1024 + cs * 32 + pc8, &ostage[prow64 * 32 + pc8]);
      if (tid == 0){
        asm volatile("s_waitcnt vmcnt(0)" ::: "memory");
        __hip_atomic_store(myflag, 2 * t + 1, __ATOMIC_RELAXED, __HIP_MEMORY_SCOPE_AGENT);
      }
      if (w == 0) waitflags32(fgrp, 2 * t + 1);
      __syncthreads();
      stage_in(rh_w, stage, tid);
      __syncthreads();
    }
    float hn[4];
    if (w == 4 || w == 5){
      f32x4 a0 = {0.f,0.f,0.f,0.f}, a1 = {0.f,0.f,0.f,0.f};
      if (t){
        const char* sb = (const char*)stage;
        #pragma unroll
        for (int i = 0; i < 32; i += 2){
          short8 f0 = *(const short8*)(sb + ((abase + i * 64) ^ asw));
          short8 f1 = *(const short8*)(sb + ((abase + i * 64 + 64) ^ asw));
          a0 = MFMA(f0, wreg[i],     a0, 0, 0, 0);
          a1 = MFMA(f1, wreg[i + 1], a1, 0, 0, 0);
        }
      }
      #pragma unroll
      for (int j = 0; j < 4; ++j){
        int i33 = (erow0 + j) * 33 + ecol;
        float ht = tanh_fast(a0[j] + a1[j] + b2f((unsigned short)(gx >> (16 * j))));
        float z  = zlds[i33], hp = hlds[i33];
        hn[j] = z * hp + (1.0f - z) * ht;
        hlds[i33] = hn[j];
        ostage[(erow0 + j) * 32 + ecol] = f2b(hn[j]);
      }
    }
    __syncthreads();                                   // ostage / hlds complete
    if (t < T_STEPS - 1){
      if (tid < 64) pub16(hb_w + prow64 * 1024 + cs * 32 + pc8, &ostage[prow64 * 32 + pc8]);
      if (tid == 0){
        asm volatile("s_waitcnt vmcnt(0)" ::: "memory");
        __hip_atomic_store(myflag, 2 * t + 2, __ATOMIC_RELAXED, __HIP_MEMORY_SCOPE_AGENT);
      }
    }
    // out stores: after the flag release, off the critical path
    if (w == 4 || w == 5){
      #pragma unroll
      for (int j = 0; j < 4; ++j){
        __builtin_nontemporal_store(hn[j],
            &out[((size_t)t * BATCH + rg * 16 + erow0 + j) * HID + col]);
        if (t == T_STEPS - 1)
          __builtin_nontemporal_store(hn[j],
              &out[(size_t)T_STEPS * BATCH * HID + (size_t)(rg * 16 + erow0 + j) * HID + col]);
      }
    }
  }
}

extern "C" void kernel_launch(void* const* d_in, const int* in_sizes, int n_in,
                              void* d_out, int out_size, void* d_ws, size_t ws_size,
                              hipStream_t stream){
  const float* inputs = (const float*)d_in[0];
  const float* W_xz = (const float*)d_in[1];
  const float* W_hz = (const float*)d_in[2];
  const float* b_z  = (const float*)d_in[3];
  const float* W_xr = (const float*)d_in[4];
  const float* W_hr = (const float*)d_in[5];
  const float* b_r  = (const float*)d_in[6];
  const float* W_xh = (const float*)d_in[7];
  const float* W_hh = (const float*)d_in[8];
  const float* b_h  = (const float*)d_in[9];
  float* out = (float*)d_out;

  char* ws = (char*)d_ws;
  int*            flags = (int*)ws;                                  // 16 KiB (128B-strided)
  unsigned short* hb    = (unsigned short*)(ws + 16384);             // 4 MiB (32 slots)
  unsigned short* rh    = (unsigned short*)(ws + 16384 + 4194304);   // 4 MiB
  unsigned short* wt    = (unsigned short*)(ws + 16384 + 8388608);   // 12 MiB
  unsigned short* G2    = (unsigned short*)(ws + 16384 + 8388608 + 12582912); // 192 MiB
  // total ws needed: ~212 MB

  gru_init_k<<<16, 256, 0, stream>>>(flags);
  gru_prepw_k<<<dim3(32, 32, 6), dim3(32, 8), 0, stream>>>(W_xz, W_hz, W_xr, W_hr, W_xh, W_hh, wt);
  gru_xproj_k<<<dim3(1024, 3), 512, 0, stream>>>(inputs, wt, b_z, b_r, b_h, G2);
  gru_scan_k<<<NWG, 512, 0, stream>>>(G2, wt, out, hb, rh, flags);
}

// Round 16
// 3756.245 us; speedup vs baseline: 1.3050x; 1.0089x over previous
//
#include <hip/hip_runtime.h>
#include <hip/hip_bf16.h>

#define T_STEPS 512
#define BATCH   64
#define HID     1024
#define NWG     128         // 4 row-groups x 32 col-slices (32 cols each)
#define NSLOT   32          // rotating exchange slots
#define SLOT_SH (4 * 16 * 1024)   // shorts per slot

typedef __attribute__((ext_vector_type(8))) short short8;
typedef __attribute__((ext_vector_type(4))) float f32x4;
typedef __attribute__((ext_vector_type(4))) int  i32x4;

static __device__ __forceinline__ float b2f(unsigned short u){
  union { unsigned u; float f; } c; c.u = ((unsigned)u) << 16; return c.f;
}
static __device__ __forceinline__ unsigned short f2b(float f){
  union { float f; unsigned u; } c; c.f = f;
  unsigned r = c.u + 0x7fffu + ((c.u >> 16) & 1u);
  return (unsigned short)(r >> 16);
}
static __device__ __forceinline__ float sigm(float x){ return 1.0f / (1.0f + __expf(-x)); }
static __device__ __forceinline__ float tanh_fast(float x){ return 2.0f / (1.0f + __expf(-2.0f * x)) - 1.0f; }

#define MFMA __builtin_amdgcn_mfma_f32_16x16x32_bf16

// ---------------- init: zero barrier flags (1 flag per 128B line) ----------------
__global__ void gru_init_k(int* __restrict__ flags){
  int i = blockIdx.x * blockDim.x + threadIdx.x;
  if (i < 4 * 32 * 32)
    __hip_atomic_store(flags + i, 0, __ATOMIC_RELAXED, __HIP_MEMORY_SCOPE_AGENT);
}

// ---------------- transpose + cast weights: Wt[g][n][k] = W_g[k][n] ----------------
__global__ void gru_prepw_k(const float* __restrict__ w0, const float* __restrict__ w1,
                            const float* __restrict__ w2, const float* __restrict__ w3,
                            const float* __restrict__ w4, const float* __restrict__ w5,
                            unsigned short* __restrict__ wt){
  __shared__ float tile[32][33];
  const float* src;
  switch (blockIdx.z){
    case 0: src = w0; break; case 1: src = w1; break; case 2: src = w2; break;
    case 3: src = w3; break; case 4: src = w4; break; default: src = w5; break;
  }
  int tx = threadIdx.x, ty = threadIdx.y;
  int x0 = blockIdx.x * 32, y0 = blockIdx.y * 32;
  #pragma unroll
  for (int i = 0; i < 32; i += 8)
    tile[ty + i][tx] = src[(size_t)(y0 + ty + i) * HID + x0 + tx];
  __syncthreads();
  unsigned short* dst = wt + (size_t)blockIdx.z * HID * HID;
  #pragma unroll
  for (int i = 0; i < 32; i += 8)
    dst[(size_t)(x0 + ty + i) * HID + y0 + tx] = f2b(tile[tx][ty + i]);
}

// ---------------- pre-pass: G2[t][gate][rh][col][row32] = (X @ Wx + b), bf16 ----------
// block: 32 batch-rows (rh = blockIdx.x&1) x ONE gate (1024 cols). Block's output region
// is a CONTIGUOUS 64KB slab -> dense coalesced writes.
__global__ __launch_bounds__(512, 1) void gru_xproj_k(
    const float* __restrict__ inp,         // [32768][1024] fp32
    const unsigned short* __restrict__ wt, // x-weights slots 0,2,4
    const float* __restrict__ bz, const float* __restrict__ br, const float* __restrict__ bh,
    unsigned short* __restrict__ G2)       // [512][3][2][1024][32] bf16
{
  __shared__ __align__(16) unsigned short albs[32 * 1024];   // 64 KiB swizzled A-tile

  const int tid = threadIdx.x, wv = tid >> 6, lane = tid & 63;
  const int l16 = lane & 15, kq = lane >> 4;
  const int tt = blockIdx.x >> 1;
  const int rh = blockIdx.x & 1;
  const int rbase = rh * 32;
  const int g = blockIdx.y;
  const float* bias_p = (g == 0) ? bz : (g == 1) ? br : bh;

  // stage + convert A: 32 rows x 1024 k, fp32 -> bf16, swizzle byte b ^ ((b>>11&7)<<4)
  char* sb = (char*)albs;
  const float* abase = inp + ((size_t)tt * 64 + rbase) * HID;
  #pragma unroll
  for (int p = 0; p < 16; ++p){
    int e = (p * 512 + tid) * 4;                 // element in [32][1024]
    float4 v = *(const float4*)(abase + e);
    ushort4 o;
    o.x = f2b(v.x); o.y = f2b(v.y); o.z = f2b(v.z); o.w = f2b(v.w);
    int b = e * 2;
    *(ushort4*)(sb + (b ^ (((b >> 11) & 7) << 4))) = o;
  }
  __syncthreads();

  const int n0 = wv * 128;
  const unsigned short* wslab = wt + (size_t)(2 * g) * HID * HID;
  const unsigned short* wcol[8];
  float bias[8];
  #pragma unroll
  for (int c = 0; c < 8; ++c){
    int n = n0 + c * 16 + l16;
    wcol[c] = wslab + (size_t)n * HID + kq * 8;
    bias[c] = bias_p[n];
  }

  f32x4 acc[2][8];
  #pragma unroll
  for (int r = 0; r < 2; ++r)
    #pragma unroll
    for (int c = 0; c < 8; ++c) acc[r][c] = (f32x4){0.f,0.f,0.f,0.f};

  const int asw = (l16 & 7) << 4;
  for (int kk = 0; kk < HID; kk += 32){
    short8 a0 = *(const short8*)(sb + ((l16 * 2048 + kk * 2 + kq * 16) ^ asw));
    short8 a1 = *(const short8*)(sb + (((16 + l16) * 2048 + kk * 2 + kq * 16) ^ asw));
    #pragma unroll
    for (int c = 0; c < 8; ++c){
      short8 bf = *(const short8*)(wcol[c] + kk);
      acc[0][c] = MFMA(a0, bf, acc[0][c], 0, 0, 0);
      acc[1][c] = MFMA(a1, bf, acc[1][c], 0, 0, 0);
    }
  }

  // contiguous 64KB output slab for this block: [1024 cols][32 rows]
  unsigned short* gout = G2 + (((size_t)tt * 3 + g) * 2 + rh) * 32768;
  #pragma unroll
  for (int c = 0; c < 8; ++c){
    int n = n0 + c * 16 + l16;
    #pragma unroll
    for (int r = 0; r < 2; ++r){
      unsigned lo = (unsigned)f2b(acc[r][c][0] + bias[c]) | ((unsigned)f2b(acc[r][c][1] + bias[c]) << 16);
      unsigned hi = (unsigned)f2b(acc[r][c][2] + bias[c]) | ((unsigned)f2b(acc[r][c][3] + bias[c]) << 16);
      *(unsigned long long*)&gout[(size_t)n * 32 + r * 16 + kq * 4] =
        (unsigned long long)lo | ((unsigned long long)hi << 32);
    }
  }
}

// ---- poll: 32 lanes, one flag each (flags 128B apart), light backoff ----
static __device__ __forceinline__ void waitflags32(const int* fgrp, int target){
  const int lane = threadIdx.x & 63;
  const int* p = fgrp + (lane & 31) * 32;
  const bool mine = lane < 32;
  for (;;){
    int v = mine ? __hip_atomic_load(p, __ATOMIC_RELAXED, __HIP_MEMORY_SCOPE_AGENT)
                 : 0x7fffffff;
    if (__all(v >= target)) return;
    __builtin_amdgcn_s_sleep(1);
  }
}

// ---- stage 16x1024 bf16 tile (32KB): lane-contiguous 16B chunks, conflict-free writes ----
static __device__ __forceinline__ void stage_in(const unsigned short* __restrict__ src,
                                                unsigned short* __restrict__ stg, int tid){
  char* sb = (char*)stg;
  const char* sc = (const char*)src;
  #pragma unroll
  for (int c = 0; c < 4; ++c){
    const int b = tid * 16 + c * 8192;
    short8 v = __builtin_nontemporal_load((const short8*)(sc + b));
    *(short8*)(sb + (b ^ (((b >> 11) & 7) << 4))) = v;
  }
}

// ---- publish 16B write-through to MALL (sc0 sc1) ----
static __device__ __forceinline__ void pub16(unsigned short* dst, const unsigned short* lds_src){
  i32x4 v = *(const i32x4*)lds_src;
  asm volatile("global_store_dwordx4 %0, %1, off sc0 sc1" :: "v"(dst), "v"(v) : "memory");
}

// ---------------- persistent GRU scan: full-K wave roles; wave-7 publishes, wave-0 polls ----
// waves 0-1: Z (col-tiles 0,1) | waves 2-3: R | waves 4-5: H_tilde | waves 6-7: stage/publish
__global__ __launch_bounds__(512, 1) void gru_scan_k(
    const unsigned short* __restrict__ G2,    // [512][3][2][1024][32] bf16
    const unsigned short* __restrict__ wt,    // [6][1024][1024] bf16 [n][k]
    float* __restrict__ out,                  // [T][64][1024] fp32 + [64][1024] H_final
    unsigned short* __restrict__ hb,          // [NSLOT][4][16][1024] bf16 H slots
    unsigned short* __restrict__ rh,          // [NSLOT][4][16][1024] bf16 R*H slots
    int* __restrict__ flags)                  // [4][32][32] (128B-strided flags)
{
  __shared__ __align__(16) unsigned short stage[16 * 1024];  // 32 KiB staged H or R*H
  __shared__ float zlds[16 * 33];                            // own-slice Z (padded)
  __shared__ float hlds[16 * 33];                            // own-slice H fp32 (padded)
  __shared__ __align__(16) unsigned short ostage[512];       // 1 KiB publish tile

  const int bid = blockIdx.x;
  const int rg  = bid & 3;            // batch rows [rg*16, +16)
  const int cs  = bid >> 2;           // hid cols  [cs*32, +32)
  const int tid  = threadIdx.x;
  const int w    = tid >> 6;
  const int lane = tid & 63;
  const int l16  = lane & 15;
  const int kq   = lane >> 4;

  const int myct = (w < 4) ? (w & 1) : ((w < 6) ? (w - 4) : 0);
  const int col  = cs * 32 + myct * 16 + l16;   // this role's global hid col
  const int gA   = (w >> 1) & 1;                // waves0-1: Z(0), waves2-3: R(1)
  const int erow0 = kq * 4;                     // acc[j] -> batch row erow0+j
  const int ecol  = myct * 16 + l16;

  // ---- weights into registers, one array per wave role ----
  short8 wreg[32];
  if (w < 6){
    const int slot = (w < 2) ? 1 : (w < 4) ? 3 : 5;   // Whz / Whr / Whh
    const unsigned short* p = wt + (size_t)slot * HID * HID + (size_t)col * HID + kq * 8;
    #pragma unroll
    for (int i = 0; i < 32; ++i) wreg[i] = *(const short8*)(p + i * 32);
  }

  int* fgrp   = flags + rg * 32 * 32;
  int* myflag = fgrp + cs * 32;

  for (int i = tid; i < 16 * 33; i += 512) hlds[i] = 0.f;
  __syncthreads();

  const int asw = (l16 & 7) << 4;
  const int abase = l16 * 2048 + kq * 16;        // + i*64, then ^asw
  const int pidx = tid - 448;                    // publish mapping (wave 7)
  const int prow = pidx >> 2, pc8 = (pidx & 3) * 8;

  // G2 read base offsets (layout [t][gate][rh][col][row32])
  const size_t g2rh = (size_t)(rg >> 1) * 32768;
  const int    g2r  = (rg & 1) * 16 + erow0;

  for (int t = 0; t < T_STEPS; ++t){
    unsigned short* hb_w = hb + (size_t)(t & (NSLOT - 1)) * SLOT_SH + rg * 16384;
    unsigned short* rh_w = rh + (size_t)(t & (NSLOT - 1)) * SLOT_SH + rg * 16384;
    const unsigned short* hb_r = hb + (size_t)((t - 1) & (NSLOT - 1)) * SLOT_SH + rg * 16384;

    // per-role x-gate scalars (cached, before any wait): 4 rows x 1 col = one u64
    unsigned long long gx = 0;
    if (w < 6){
      const int gate = (w < 4) ? gA : 2;
      gx = *(const unsigned long long*)
           (G2 + ((size_t)t * 3 + gate) * 65536 + g2rh + (size_t)col * 32 + g2r);
    }

    // ---- phase A: Z / R gates (waves 0-3, full K) ----
    if (t){
      if (w == 0) waitflags32(fgrp, 2 * t);
      __syncthreads();
      stage_in(hb_r, stage, tid);
      __syncthreads();
    }
    if (w < 4){
      f32x4 a0 = {0.f,0.f,0.f,0.f}, a1 = {0.f,0.f,0.f,0.f};
      if (t){
        const char* sb = (const char*)stage;
        #pragma unroll
        for (int i = 0; i < 32; i += 2){
          short8 f0 = *(const short8*)(sb + ((abase + i * 64) ^ asw));
          short8 f1 = *(const short8*)(sb + ((abase + i * 64 + 64) ^ asw));
          a0 = MFMA(f0, wreg[i],     a0, 0, 0, 0);
          a1 = MFMA(f1, wreg[i + 1], a1, 0, 0, 0);
        }
      }
      #pragma unroll
      for (int j = 0; j < 4; ++j){
        float g = sigm(a0[j] + a1[j] + b2f((unsigned short)(gx >> (16 * j))));
        if (w < 2) zlds[(erow0 + j) * 33 + ecol] = g;                       // Z
        else       ostage[(erow0 + j) * 32 + ecol] =
                     f2b(g * hlds[(erow0 + j) * 33 + ecol]);                // R*H
      }
    }
    __syncthreads();                                   // zlds / ostage complete

    // ---- exchange R*H: wave 7 publishes+flags while wave 0 polls concurrently ----
    if (t){
      if (tid >= 448) pub16(rh_w + prow * 1024 + cs * 32 + pc8, &ostage[prow * 32 + pc8]);
      if (tid == 448){
        asm volatile("s_waitcnt vmcnt(0)" ::: "memory");   // wave-7 scalar drain covers its 64 lanes
        __hip_atomic_store(myflag, 2 * t + 1, __ATOMIC_RELAXED, __HIP_MEMORY_SCOPE_AGENT);
      }
      if (w == 0) waitflags32(fgrp, 2 * t + 1);
      __syncthreads();
      stage_in(rh_w, stage, tid);
      __syncthreads();
    }

    // ---- phase B: H_tilde + combine (waves 4-5, full K) ----
    float hn[4];
    if (w == 4 || w == 5){
      f32x4 a0 = {0.f,0.f,0.f,0.f}, a1 = {0.f,0.f,0.f,0.f};
      if (t){
        const char* sb = (const char*)stage;
        #pragma unroll
        for (int i = 0; i < 32; i += 2){
          short8 f0 = *(const short8*)(sb + ((abase + i * 64) ^ asw));
          short8 f1 = *(const short8*)(sb + ((abase + i * 64 + 64) ^ asw));
          a0 = MFMA(f0, wreg[i],     a0, 0, 0, 0);
          a1 = MFMA(f1, wreg[i + 1], a1, 0, 0, 0);
        }
      }
      #pragma unroll
      for (int j = 0; j < 4; ++j){
        int i33 = (erow0 + j) * 33 + ecol;
        float ht = tanh_fast(a0[j] + a1[j] + b2f((unsigned short)(gx >> (16 * j))));
        float z  = zlds[i33], hp = hlds[i33];
        hn[j] = z * hp + (1.0f - z) * ht;
        hlds[i33] = hn[j];
        ostage[(erow0 + j) * 32 + ecol] = f2b(hn[j]);
      }
    }
    __syncthreads();                                   // ostage / hlds complete
    if (t < T_STEPS - 1){
      if (tid >= 448) pub16(hb_w + prow * 1024 + cs * 32 + pc8, &ostage[prow * 32 + pc8]);
      if (tid == 448){
        asm volatile("s_waitcnt vmcnt(0)" ::: "memory");
        __hip_atomic_store(myflag, 2 * t + 2, __ATOMIC_RELAXED, __HIP_MEMORY_SCOPE_AGENT);
      }
    }
    // out stores: concurrent with publish, off the critical path
    if (w == 4 || w == 5){
      #pragma unroll
      for (int j = 0; j < 4; ++j){
        __builtin_nontemporal_store(hn[j],
            &out[((size_t)t * BATCH + rg * 16 + erow0 + j) * HID + col]);
        if (t == T_STEPS - 1)
          __builtin_nontemporal_store(hn[j],
              &out[(size_t)T_STEPS * BATCH * HID + (size_t)(rg * 16 + erow0 + j) * HID + col]);
      }
    }
  }
}

extern "C" void kernel_launch(void* const* d_in, const int* in_sizes, int n_in,
                              void* d_out, int out_size, void* d_ws, size_t ws_size,
                              hipStream_t stream){
  const float* inputs = (const float*)d_in[0];
  const float* W_xz = (const float*)d_in[1];
  const float* W_hz = (const float*)d_in[2];
  const float* b_z  = (const float*)d_in[3];
  const float* W_xr = (const float*)d_in[4];
  const float* W_hr = (const float*)d_in[5];
  const float* b_r  = (const float*)d_in[6];
  const float* W_xh = (const float*)d_in[7];
  const float* W_hh = (const float*)d_in[8];
  const float* b_h  = (const float*)d_in[9];
  float* out = (float*)d_out;

  char* ws = (char*)d_ws;
  int*            flags = (int*)ws;                                  // 16 KiB (128B-strided)
  unsigned short* hb    = (unsigned short*)(ws + 16384);             // 4 MiB (32 slots)
  unsigned short* rh    = (unsigned short*)(ws + 16384 + 4194304);   // 4 MiB
  unsigned short* wt    = (unsigned short*)(ws + 16384 + 8388608);   // 12 MiB
  unsigned short* G2    = (unsigned short*)(ws + 16384 + 8388608 + 12582912); // 192 MiB
  // total ws needed: ~212 MB

  gru_init_k<<<16, 256, 0, stream>>>(flags);
  gru_prepw_k<<<dim3(32, 32, 6), dim3(32, 8), 0, stream>>>(W_xz, W_hz, W_xr, W_hr, W_xh, W_hh, wt);
  gru_xproj_k<<<dim3(1024, 3), 512, 0, stream>>>(inputs, wt, b_z, b_r, b_h, G2);
  gru_scan_k<<<NWG, 512, 0, stream>>>(G2, wt, out, hb, rh, flags);
}

// Round 17
// 3021.471 us; speedup vs baseline: 1.6223x; 1.2432x over previous
//
#include <hip/hip_runtime.h>
#include <hip/hip_bf16.h>

#define T_STEPS 512
#define BATCH   64
#define HID     1024
#define NBLK    256         // 128 scan WGs + 128 xproj workers
#define NSLOT   32          // rotating exchange slots
#define SLOT_SH (4 * 16 * 1024)   // shorts per slot

typedef __attribute__((ext_vector_type(8))) short short8;
typedef __attribute__((ext_vector_type(4))) float f32x4;
typedef __attribute__((ext_vector_type(4))) int  i32x4;

static __device__ __forceinline__ float b2f(unsigned short u){
  union { unsigned u; float f; } c; c.u = ((unsigned)u) << 16; return c.f;
}
static __device__ __forceinline__ unsigned short f2b(float f){
  union { float f; unsigned u; } c; c.f = f;
  unsigned r = c.u + 0x7fffu + ((c.u >> 16) & 1u);
  return (unsigned short)(r >> 16);
}
static __device__ __forceinline__ float sigm(float x){ return 1.0f / (1.0f + __expf(-x)); }
static __device__ __forceinline__ float tanh_fast(float x){ return 2.0f / (1.0f + __expf(-2.0f * x)) - 1.0f; }

#define MFMA __builtin_amdgcn_mfma_f32_16x16x32_bf16

// ---------------- init: zero flags + G2-ready counters ----------------
__global__ void gru_init_k(int* __restrict__ flags, int* __restrict__ gready){
  int i = blockIdx.x * blockDim.x + threadIdx.x;
  if (i < 4 * 32 * 32)
    __hip_atomic_store(flags + i, 0, __ATOMIC_RELAXED, __HIP_MEMORY_SCOPE_AGENT);
  if (i < T_STEPS * 32)
    __hip_atomic_store(gready + i, 0, __ATOMIC_RELAXED, __HIP_MEMORY_SCOPE_AGENT);
}

// ---------------- transpose + cast weights: Wt[g][n][k] = W_g[k][n] ----------------
__global__ void gru_prepw_k(const float* __restrict__ w0, const float* __restrict__ w1,
                            const float* __restrict__ w2, const float* __restrict__ w3,
                            const float* __restrict__ w4, const float* __restrict__ w5,
                            unsigned short* __restrict__ wt){
  __shared__ float tile[32][33];
  const float* src;
  switch (blockIdx.z){
    case 0: src = w0; break; case 1: src = w1; break; case 2: src = w2; break;
    case 3: src = w3; break; case 4: src = w4; break; default: src = w5; break;
  }
  int tx = threadIdx.x, ty = threadIdx.y;
  int x0 = blockIdx.x * 32, y0 = blockIdx.y * 32;
  #pragma unroll
  for (int i = 0; i < 32; i += 8)
    tile[ty + i][tx] = src[(size_t)(y0 + ty + i) * HID + x0 + tx];
  __syncthreads();
  unsigned short* dst = wt + (size_t)blockIdx.z * HID * HID;
  #pragma unroll
  for (int i = 0; i < 32; i += 8)
    dst[(size_t)(x0 + ty + i) * HID + y0 + tx] = f2b(tile[tx][ty + i]);
}

// ---- poll: 32 lanes, one flag each (flags 128B apart), light backoff ----
static __device__ __forceinline__ void waitflags32(const int* fgrp, int target){
  const int lane = threadIdx.x & 63;
  const int* p = fgrp + (lane & 31) * 32;
  const bool mine = lane < 32;
  for (;;){
    int v = mine ? __hip_atomic_load(p, __ATOMIC_RELAXED, __HIP_MEMORY_SCOPE_AGENT)
                 : 0x7fffffff;
    if (__all(v >= target)) return;
    __builtin_amdgcn_s_sleep(1);
  }
}

// ---- stage 16x1024 bf16 tile (32KB): lane-contiguous 16B chunks ----
static __device__ __forceinline__ void stage_in(const unsigned short* __restrict__ src,
                                                unsigned short* __restrict__ stg, int tid){
  char* sb = (char*)stg;
  const char* sc = (const char*)src;
  #pragma unroll
  for (int c = 0; c < 4; ++c){
    const int b = tid * 16 + c * 8192;
    short8 v = __builtin_nontemporal_load((const short8*)(sc + b));
    *(short8*)(sb + (b ^ (((b >> 11) & 7) << 4))) = v;
  }
}

// ---- write-through stores to MALL (sc0 sc1) ----
static __device__ __forceinline__ void pub16(unsigned short* dst, const unsigned short* lds_src){
  i32x4 v = *(const i32x4*)lds_src;
  asm volatile("global_store_dwordx4 %0, %1, off sc0 sc1" :: "v"(dst), "v"(v) : "memory");
}
static __device__ __forceinline__ void pub8(unsigned short* dst, unsigned long long v){
  asm volatile("global_store_dwordx2 %0, %1, off sc0 sc1" :: "v"(dst), "v"(v) : "memory");
}

// ---------------- merged kernel: 128 scan WGs + 128 xproj workers ----------------
__global__ __launch_bounds__(512, 1) void gru_main_k(
    const float* __restrict__ inp,            // [32768][1024] fp32
    const unsigned short* __restrict__ wt,    // [6][1024][1024] bf16 [n][k]
    const float* __restrict__ bz, const float* __restrict__ br, const float* __restrict__ bh,
    unsigned short* __restrict__ G2,          // [512][3][2][1024][32] bf16
    float* __restrict__ out,                  // [T][64][1024] fp32 + [64][1024] H_final
    unsigned short* __restrict__ hb,          // [NSLOT][4][16][1024] bf16 H slots
    unsigned short* __restrict__ rh,          // [NSLOT][4][16][1024] bf16 R*H slots
    int* __restrict__ flags,                  // [4][32][32] (128B-strided)
    int* __restrict__ gready)                 // [512][32] (128B-strided)
{
  __shared__ __align__(16) char smem[98304];  // 96 KiB -> exactly 1 WG/CU
  const int bid = blockIdx.x;
  const int tid = threadIdx.x;

  if (bid >= 128){
    // ================= xproj worker: 24 tiles in ascending-t order =================
    const int d = bid - 128;
    const int wv = tid >> 6, lane = tid & 63;
    const int l16 = lane & 15, kq = lane >> 4;
    char* sb = (char*)smem;                       // 64 KiB A-tile
    const int asw = (l16 & 7) << 4;

    for (int i = 0; i < 24; ++i){
      const int tau = i * 128 + d;
      const int tt = tau / 6, rem = tau % 6, g = rem >> 1, rhh = rem & 1;
      const float* bias_p = (g == 0) ? bz : (g == 1) ? br : bh;

      // stage + convert A: 32 rows x 1024 k, fp32 -> bf16, swizzled
      const float* abase = inp + ((size_t)tt * 64 + rhh * 32) * HID;
      #pragma unroll
      for (int p = 0; p < 16; ++p){
        int e = (p * 512 + tid) * 4;
        float4 v = *(const float4*)(abase + e);
        ushort4 o;
        o.x = f2b(v.x); o.y = f2b(v.y); o.z = f2b(v.z); o.w = f2b(v.w);
        int b = e * 2;
        *(ushort4*)(sb + (b ^ (((b >> 11) & 7) << 4))) = o;
      }
      __syncthreads();

      const int n0 = wv * 128;
      const unsigned short* wslab = wt + (size_t)(2 * g) * HID * HID;
      const unsigned short* wcol[8];
      float bias[8];
      #pragma unroll
      for (int c = 0; c < 8; ++c){
        int n = n0 + c * 16 + l16;
        wcol[c] = wslab + (size_t)n * HID + kq * 8;
        bias[c] = bias_p[n];
      }
      f32x4 acc[2][8];
      #pragma unroll
      for (int r = 0; r < 2; ++r)
        #pragma unroll
        for (int c = 0; c < 8; ++c) acc[r][c] = (f32x4){0.f,0.f,0.f,0.f};

      for (int kk = 0; kk < HID; kk += 32){
        short8 a0 = *(const short8*)(sb + ((l16 * 2048 + kk * 2 + kq * 16) ^ asw));
        short8 a1 = *(const short8*)(sb + (((16 + l16) * 2048 + kk * 2 + kq * 16) ^ asw));
        #pragma unroll
        for (int c = 0; c < 8; ++c){
          short8 bf = *(const short8*)(wcol[c] + kk);
          acc[0][c] = MFMA(a0, bf, acc[0][c], 0, 0, 0);
          acc[1][c] = MFMA(a1, bf, acc[1][c], 0, 0, 0);
        }
      }

      // contiguous 64KB slab, write-through to MALL
      unsigned short* gout = G2 + (((size_t)tt * 3 + g) * 2 + rhh) * 32768;
      #pragma unroll
      for (int c = 0; c < 8; ++c){
        int n = n0 + c * 16 + l16;
        #pragma unroll
        for (int r = 0; r < 2; ++r){
          unsigned lo = (unsigned)f2b(acc[r][c][0] + bias[c]) | ((unsigned)f2b(acc[r][c][1] + bias[c]) << 16);
          unsigned hi = (unsigned)f2b(acc[r][c][2] + bias[c]) | ((unsigned)f2b(acc[r][c][3] + bias[c]) << 16);
          pub8(&gout[(size_t)n * 32 + r * 16 + kq * 4],
               (unsigned long long)lo | ((unsigned long long)hi << 32));
        }
      }
      asm volatile("s_waitcnt vmcnt(0)" ::: "memory");   // per-thread drain
      __syncthreads();                                   // all 512 threads drained; smem reusable
      if (tid == 0)
        __hip_atomic_fetch_add(gready + tt * 32, 1, __ATOMIC_RELAXED, __HIP_MEMORY_SCOPE_AGENT);
    }
    return;
  }

  // ================= scan WG (byte-identical structure to r16) =================
  unsigned short* stage  = (unsigned short*)smem;            // 32 KiB
  float*          zlds   = (float*)(smem + 32768);           // 16*33 fp32
  float*          hlds   = (float*)(smem + 34880);           // 16*33 fp32
  unsigned short* ostage = (unsigned short*)(smem + 36992);  // 1 KiB

  const int rg  = bid & 3;
  const int cs  = bid >> 2;
  const int w    = tid >> 6;
  const int lane = tid & 63;
  const int l16  = lane & 15;
  const int kq   = lane >> 4;

  const int myct = (w < 4) ? (w & 1) : ((w < 6) ? (w - 4) : 0);
  const int col  = cs * 32 + myct * 16 + l16;
  const int gA   = (w >> 1) & 1;
  const int erow0 = kq * 4;
  const int ecol  = myct * 16 + l16;

  short8 wreg[32];
  if (w < 6){
    const int slot = (w < 2) ? 1 : (w < 4) ? 3 : 5;
    const unsigned short* p = wt + (size_t)slot * HID * HID + (size_t)col * HID + kq * 8;
    #pragma unroll
    for (int i = 0; i < 32; ++i) wreg[i] = *(const short8*)(p + i * 32);
  }

  int* fgrp   = flags + rg * 32 * 32;
  int* myflag = fgrp + cs * 32;

  for (int i = tid; i < 16 * 33; i += 512) hlds[i] = 0.f;
  __syncthreads();

  const int asw = (l16 & 7) << 4;
  const int abase = l16 * 2048 + kq * 16;
  const int pidx = tid - 448;
  const int prow = pidx >> 2, pc8 = (pidx & 3) * 8;

  const size_t g2rh = (size_t)(rg >> 1) * 32768;
  const int    g2r  = (rg & 1) * 16 + erow0;

  for (int t = 0; t < T_STEPS; ++t){
    unsigned short* hb_w = hb + (size_t)(t & (NSLOT - 1)) * SLOT_SH + rg * 16384;
    unsigned short* rh_w = rh + (size_t)(t & (NSLOT - 1)) * SLOT_SH + rg * 16384;
    const unsigned short* hb_r = hb + (size_t)((t - 1) & (NSLOT - 1)) * SLOT_SH + rg * 16384;

    // gate availability of this step's G2 tile (passes instantly in steady state)
    unsigned long long gx = 0;
    if (w < 6){
      const int* gp = gready + t * 32;
      int v = (lane == 0) ? __hip_atomic_load(gp, __ATOMIC_RELAXED, __HIP_MEMORY_SCOPE_AGENT) : 6;
      while (!__all(v >= 6)){
        __builtin_amdgcn_s_sleep(2);
        v = (lane == 0) ? __hip_atomic_load(gp, __ATOMIC_RELAXED, __HIP_MEMORY_SCOPE_AGENT) : 6;
      }
      const int gate = (w < 4) ? gA : 2;
      gx = __hip_atomic_load((const unsigned long long*)
             (G2 + ((size_t)t * 3 + gate) * 65536 + g2rh + (size_t)col * 32 + g2r),
             __ATOMIC_RELAXED, __HIP_MEMORY_SCOPE_AGENT);
    }

    // ---- phase A: Z / R gates (waves 0-3, full K) ----
    if (t){
      if (w == 0) waitflags32(fgrp, 2 * t);
      __syncthreads();
      stage_in(hb_r, stage, tid);
      __syncthreads();
    }
    if (w < 4){
      f32x4 a0 = {0.f,0.f,0.f,0.f}, a1 = {0.f,0.f,0.f,0.f};
      if (t){
        const char* sb = (const char*)stage;
        #pragma unroll
        for (int i = 0; i < 32; i += 2){
          short8 f0 = *(const short8*)(sb + ((abase + i * 64) ^ asw));
          short8 f1 = *(const short8*)(sb + ((abase + i * 64 + 64) ^ asw));
          a0 = MFMA(f0, wreg[i],     a0, 0, 0, 0);
          a1 = MFMA(f1, wreg[i + 1], a1, 0, 0, 0);
        }
      }
      #pragma unroll
      for (int j = 0; j < 4; ++j){
        float g = sigm(a0[j] + a1[j] + b2f((unsigned short)(gx >> (16 * j))));
        if (w < 2) zlds[(erow0 + j) * 33 + ecol] = g;
        else       ostage[(erow0 + j) * 32 + ecol] =
                     f2b(g * hlds[(erow0 + j) * 33 + ecol]);
      }
    }
    __syncthreads();

    // ---- exchange R*H: wave 7 publishes+flags while wave 0 polls ----
    if (t){
      if (tid >= 448) pub16(rh_w + prow * 1024 + cs * 32 + pc8, &ostage[prow * 32 + pc8]);
      if (tid == 448){
        asm volatile("s_waitcnt vmcnt(0)" ::: "memory");
        __hip_atomic_store(myflag, 2 * t + 1, __ATOMIC_RELAXED, __HIP_MEMORY_SCOPE_AGENT);
      }
      if (w == 0) waitflags32(fgrp, 2 * t + 1);
      __syncthreads();
      stage_in(rh_w, stage, tid);
      __syncthreads();
    }

    // ---- phase B: H_tilde + combine (waves 4-5, full K) ----
    float hn[4];
    if (w == 4 || w == 5){
      f32x4 a0 = {0.f,0.f,0.f,0.f}, a1 = {0.f,0.f,0.f,0.f};
      if (t){
        const char* sb = (const char*)stage;
        #pragma unroll
        for (int i = 0; i < 32; i += 2){
          short8 f0 = *(const short8*)(sb + ((abase + i * 64) ^ asw));
          short8 f1 = *(const short8*)(sb + ((abase + i * 64 + 64) ^ asw));
          a0 = MFMA(f0, wreg[i],     a0, 0, 0, 0);
          a1 = MFMA(f1, wreg[i + 1], a1, 0, 0, 0);
        }
      }
      #pragma unroll
      for (int j = 0; j < 4; ++j){
        int i33 = (erow0 + j) * 33 + ecol;
        float ht = tanh_fast(a0[j] + a1[j] + b2f((unsigned short)(gx >> (16 * j))));
        float z  = zlds[i33], hp = hlds[i33];
        hn[j] = z * hp + (1.0f - z) * ht;
        hlds[i33] = hn[j];
        ostage[(erow0 + j) * 32 + ecol] = f2b(hn[j]);
      }
    }
    __syncthreads();
    if (t < T_STEPS - 1){
      if (tid >= 448) pub16(hb_w + prow * 1024 + cs * 32 + pc8, &ostage[prow * 32 + pc8]);
      if (tid == 448){
        asm volatile("s_waitcnt vmcnt(0)" ::: "memory");
        __hip_atomic_store(myflag, 2 * t + 2, __ATOMIC_RELAXED, __HIP_MEMORY_SCOPE_AGENT);
      }
    }
    if (w == 4 || w == 5){
      #pragma unroll
      for (int j = 0; j < 4; ++j){
        __builtin_nontemporal_store(hn[j],
            &out[((size_t)t * BATCH + rg * 16 + erow0 + j) * HID + col]);
        if (t == T_STEPS - 1)
          __builtin_nontemporal_store(hn[j],
              &out[(size_t)T_STEPS * BATCH * HID + (size_t)(rg * 16 + erow0 + j) * HID + col]);
      }
    }
  }
}

extern "C" void kernel_launch(void* const* d_in, const int* in_sizes, int n_in,
                              void* d_out, int out_size, void* d_ws, size_t ws_size,
                              hipStream_t stream){
  const float* inputs = (const float*)d_in[0];
  const float* W_xz = (const float*)d_in[1];
  const float* W_hz = (const float*)d_in[2];
  const float* b_z  = (const float*)d_in[3];
  const float* W_xr = (const float*)d_in[4];
  const float* W_hr = (const float*)d_in[5];
  const float* b_r  = (const float*)d_in[6];
  const float* W_xh = (const float*)d_in[7];
  const float* W_hh = (const float*)d_in[8];
  const float* b_h  = (const float*)d_in[9];
  float* out = (float*)d_out;

  char* ws = (char*)d_ws;
  int*            flags  = (int*)ws;                                 // 16 KiB (128B-strided)
  int*            gready = (int*)(ws + 16384);                       // 64 KiB (128B-strided)
  unsigned short* hb     = (unsigned short*)(ws + 81920);            // 4 MiB (32 slots)
  unsigned short* rh     = (unsigned short*)(ws + 81920 + 4194304);  // 4 MiB
  unsigned short* wt     = (unsigned short*)(ws + 81920 + 8388608);  // 12 MiB
  unsigned short* G2     = (unsigned short*)(ws + 81920 + 8388608 + 12582912); // 192 MiB
  // total ws needed: ~213 MB

  gru_init_k<<<64, 256, 0, stream>>>(flags, gready);
  gru_prepw_k<<<dim3(32, 32, 6), dim3(32, 8), 0, stream>>>(W_xz, W_hz, W_xr, W_hr, W_xh, W_hh, wt);
  gru_main_k<<<NBLK, 512, 0, stream>>>(inputs, wt, b_z, b_r, b_h, G2, out, hb, rh, flags, gready);
}